// Round 1
// baseline (1635.280 us; speedup 1.0000x reference)
//
#include <hip/hip_runtime.h>
#include <math.h>

#define N_NODES 100000
#define NFEAT 512
#define NHID 128
#define NCLASS 40

// ---------------------------------------------------------------------------
// row_ptr[i] = lower_bound(rows, i) for i in [0, N_NODES]; rows is sorted.
// ---------------------------------------------------------------------------
__global__ void rowptr_kernel(const int* __restrict__ rows, int* __restrict__ rowptr, int nE) {
    int i = blockIdx.x * blockDim.x + threadIdx.x;
    if (i > N_NODES) return;
    int lo = 0, hi = nE;
    while (lo < hi) {
        int mid = (lo + hi) >> 1;
        if (rows[mid] < i) lo = mid + 1; else hi = mid;
    }
    rowptr[i] = lo;
}

// ---------------------------------------------------------------------------
// fc1: h0 = relu(x @ W + b)   x:[N,512] W:[512,128] b:[128]
// Tile: 32 rows x 128 cols, K-chunks of 32. 256 threads, 4x4 register block.
// ---------------------------------------------------------------------------
__global__ void fc1_kernel(const float* __restrict__ x, const float* __restrict__ w,
                           const float* __restrict__ b, float* __restrict__ h0) {
    __shared__ float xs[32][33];
    __shared__ float ws[32][128];
    const int r0 = blockIdx.x * 32;
    const int tid = threadIdx.x;
    const int cg = tid & 31;   // col group -> cols cg*4 .. cg*4+3
    const int rg = tid >> 5;   // row group -> rows rg*4 .. rg*4+3

    float acc[4][4] = {};

    for (int kc = 0; kc < NFEAT; kc += 32) {
        // stage A tile (32x32)
        {
            int row = tid >> 3, q = tid & 7;
            float4 v = *reinterpret_cast<const float4*>(x + (r0 + row) * NFEAT + kc + q * 4);
            xs[row][q * 4 + 0] = v.x; xs[row][q * 4 + 1] = v.y;
            xs[row][q * 4 + 2] = v.z; xs[row][q * 4 + 3] = v.w;
        }
        // stage W tile (32x128)
        #pragma unroll
        for (int j = 0; j < 4; ++j) {
            int idx = tid + j * 256;
            int kk = idx >> 5, c4 = idx & 31;
            *reinterpret_cast<float4*>(&ws[kk][c4 * 4]) =
                *reinterpret_cast<const float4*>(w + (kc + kk) * NHID + c4 * 4);
        }
        __syncthreads();
        #pragma unroll
        for (int kk = 0; kk < 32; ++kk) {
            float4 bv = *reinterpret_cast<const float4*>(&ws[kk][cg * 4]);
            float av[4];
            #pragma unroll
            for (int m = 0; m < 4; ++m) av[m] = xs[rg * 4 + m][kk];
            #pragma unroll
            for (int m = 0; m < 4; ++m) {
                acc[m][0] = fmaf(av[m], bv.x, acc[m][0]);
                acc[m][1] = fmaf(av[m], bv.y, acc[m][1]);
                acc[m][2] = fmaf(av[m], bv.z, acc[m][2]);
                acc[m][3] = fmaf(av[m], bv.w, acc[m][3]);
            }
        }
        __syncthreads();
    }

    #pragma unroll
    for (int m = 0; m < 4; ++m) {
        int r = r0 + rg * 4 + m;
        int c = cg * 4;
        float4 o;
        o.x = fmaxf(acc[m][0] + b[c + 0], 0.f);
        o.y = fmaxf(acc[m][1] + b[c + 1], 0.f);
        o.z = fmaxf(acc[m][2] + b[c + 2], 0.f);
        o.w = fmaxf(acc[m][3] + b[c + 3], 0.f);
        *reinterpret_cast<float4*>(h0 + r * NHID + c) = o;
    }
}

// ---------------------------------------------------------------------------
// SpMM + residual mix: support[n,:] = 0.9 * sum_e vals[e]*h[cols[e],:] + 0.1*h0[n,:]
// One 128-thread group per node (feature-parallel), atomic-free via rowptr.
// ---------------------------------------------------------------------------
__global__ void spmm_kernel(const float* __restrict__ h, const float* __restrict__ h0,
                            const int* __restrict__ rowptr, const int* __restrict__ cols,
                            const float* __restrict__ vals, float* __restrict__ support) {
    int node = blockIdx.x * 2 + (threadIdx.x >> 7);
    int f = threadIdx.x & 127;
    int e0 = rowptr[node], e1 = rowptr[node + 1];
    float acc = 0.f;
    for (int e = e0; e < e1; ++e) {
        acc = fmaf(vals[e], h[cols[e] * NHID + f], acc);
    }
    int idx = node * NHID + f;
    support[idx] = 0.9f * acc + 0.1f * h0[idx];
}

// ---------------------------------------------------------------------------
// conv layer GEMM, in place: buf = relu(theta*(buf @ W) + (1-theta)*buf)
// Same tiling as fc1 but K=128. In-place is safe: each block reads only its
// own 32 rows (all reads complete before epilogue), each element re-read and
// overwritten by its single owner thread.
// ---------------------------------------------------------------------------
__global__ void layer_kernel(float* __restrict__ buf, const float* __restrict__ w, float theta) {
    __shared__ float as_[32][33];
    __shared__ float ws[32][128];
    const int r0 = blockIdx.x * 32;
    const int tid = threadIdx.x;
    const int cg = tid & 31;
    const int rg = tid >> 5;

    float acc[4][4] = {};

    for (int kc = 0; kc < NHID; kc += 32) {
        {
            int row = tid >> 3, q = tid & 7;
            float4 v = *reinterpret_cast<const float4*>(buf + (r0 + row) * NHID + kc + q * 4);
            as_[row][q * 4 + 0] = v.x; as_[row][q * 4 + 1] = v.y;
            as_[row][q * 4 + 2] = v.z; as_[row][q * 4 + 3] = v.w;
        }
        #pragma unroll
        for (int j = 0; j < 4; ++j) {
            int idx = tid + j * 256;
            int kk = idx >> 5, c4 = idx & 31;
            *reinterpret_cast<float4*>(&ws[kk][c4 * 4]) =
                *reinterpret_cast<const float4*>(w + (kc + kk) * NHID + c4 * 4);
        }
        __syncthreads();
        #pragma unroll
        for (int kk = 0; kk < 32; ++kk) {
            float4 bv = *reinterpret_cast<const float4*>(&ws[kk][cg * 4]);
            float av[4];
            #pragma unroll
            for (int m = 0; m < 4; ++m) av[m] = as_[rg * 4 + m][kk];
            #pragma unroll
            for (int m = 0; m < 4; ++m) {
                acc[m][0] = fmaf(av[m], bv.x, acc[m][0]);
                acc[m][1] = fmaf(av[m], bv.y, acc[m][1]);
                acc[m][2] = fmaf(av[m], bv.z, acc[m][2]);
                acc[m][3] = fmaf(av[m], bv.w, acc[m][3]);
            }
        }
        __syncthreads();
    }

    const float om = 1.f - theta;
    #pragma unroll
    for (int m = 0; m < 4; ++m) {
        int r = r0 + rg * 4 + m;
        int c = cg * 4;
        float4 orig = *reinterpret_cast<const float4*>(buf + r * NHID + c);
        float4 o;
        o.x = fmaxf(fmaf(theta, acc[m][0], om * orig.x), 0.f);
        o.y = fmaxf(fmaf(theta, acc[m][1], om * orig.y), 0.f);
        o.z = fmaxf(fmaf(theta, acc[m][2], om * orig.z), 0.f);
        o.w = fmaxf(fmaf(theta, acc[m][3], om * orig.w), 0.f);
        *reinterpret_cast<float4*>(buf + r * NHID + c) = o;
    }
}

// ---------------------------------------------------------------------------
// final: logits = h @ fc2_w + b; out0 = log_softmax(logits); out2 = [h, logits]
// 64 lanes per node (one wave), 4 nodes per 256-thread block.
// ---------------------------------------------------------------------------
__global__ void final_kernel(const float* __restrict__ h, const float* __restrict__ w,
                             const float* __restrict__ b, float* __restrict__ out0,
                             float* __restrict__ out2) {
    __shared__ float hs[4][128];
    const int s = threadIdx.x >> 6;
    const int lane = threadIdx.x & 63;
    const int node = blockIdx.x * 4 + s;

    float h_lo = h[node * NHID + lane];
    float h_hi = h[node * NHID + 64 + lane];
    hs[s][lane] = h_lo;
    hs[s][64 + lane] = h_hi;
    __syncthreads();

    float logit = 0.f;
    if (lane < NCLASS) {
        logit = b[lane];
        #pragma unroll 8
        for (int k = 0; k < NHID; ++k)
            logit = fmaf(hs[s][k], w[k * NCLASS + lane], logit);
    }

    float mv = (lane < NCLASS) ? logit : -1e30f;
    #pragma unroll
    for (int m = 32; m; m >>= 1) mv = fmaxf(mv, __shfl_xor(mv, m));
    float ev = (lane < NCLASS) ? __expf(logit - mv) : 0.f;
    float sum = ev;
    #pragma unroll
    for (int m = 32; m; m >>= 1) sum += __shfl_xor(sum, m);
    float lse = mv + __logf(sum);

    if (lane < NCLASS) {
        out0[node * NCLASS + lane] = logit - lse;
        out2[node * 168 + 128 + lane] = logit;
    }
    out2[node * 168 + lane] = h_lo;
    out2[node * 168 + 64 + lane] = h_hi;
}

// ---------------------------------------------------------------------------
extern "C" void kernel_launch(void* const* d_in, const int* in_sizes, int n_in,
                              void* d_out, int out_size, void* d_ws, size_t ws_size,
                              hipStream_t stream) {
    const float* x      = (const float*)d_in[0];
    const int*   rows   = (const int*)  d_in[1];
    const int*   cols   = (const int*)  d_in[2];
    const float* vals   = (const float*)d_in[3];
    const float* fc1_w  = (const float*)d_in[4];
    const float* fc1_b  = (const float*)d_in[5];
    const float* conv_w = (const float*)d_in[6];
    const float* fc2_w  = (const float*)d_in[7];
    const float* fc2_b  = (const float*)d_in[8];
    float* out = (float*)d_out;

    const int nE = in_sizes[1];
    const size_t NH = (size_t)N_NODES * NHID;   // 12.8M floats

    // workspace layout: h0 | bufA | rowptr     (~103 MB)
    float* h0   = (float*)d_ws;
    float* bufA = h0 + NH;
    int*   rowptr = (int*)(bufA + NH);

    // out regions; out1 (final h) doubles as ping-pong buffer B
    float* out0 = out;                                  // [N,40]
    float* bufB = out + (size_t)N_NODES * NCLASS;       // [N,128] == out1
    float* out2 = bufB + NH;                            // [N,168]

    rowptr_kernel<<<(N_NODES + 1 + 255) / 256, 256, 0, stream>>>(rows, rowptr, nE);
    fc1_kernel<<<N_NODES / 32, 256, 0, stream>>>(x, fc1_w, fc1_b, h0);

    const float* hcur = h0;
    float* bufs[2] = { bufA, bufB };
    for (int i = 0; i < 4; ++i) {
        float* buf = bufs[i & 1];
        float theta = logf(0.5f / (float)(i + 1) + 1.0f);
        spmm_kernel<<<N_NODES / 2, 256, 0, stream>>>(hcur, h0, rowptr, cols, vals, buf);
        layer_kernel<<<N_NODES / 32, 256, 0, stream>>>(buf, conv_w + (size_t)i * NHID * NHID, theta);
        hcur = buf;
    }

    // hcur == bufB == out1 region: final h already in place.
    final_kernel<<<N_NODES / 4, 256, 0, stream>>>(hcur, fc2_w, fc2_b, out0, out2);
}

// Round 2
// 942.404 us; speedup vs baseline: 1.7352x; 1.7352x over previous
//
#include <hip/hip_runtime.h>
#include <math.h>

#define N_NODES 100000
#define NFEAT 512
#define NHID 128
#define NCLASS 40

typedef unsigned int uint;

// pack two f32 -> bf16x2 (round-to-nearest-even)
__device__ inline uint bf16pack(float a, float b) {
    uint ua = __float_as_uint(a), ub = __float_as_uint(b);
    ua = (ua + 0x7fffu + ((ua >> 16) & 1u)) >> 16;
    ub = (ub + 0x7fffu + ((ub >> 16) & 1u)) >> 16;
    return ua | (ub << 16);
}

// ---------------------------------------------------------------------------
// row_ptr[i] = lower_bound(rows, i) for i in [0, N_NODES]; rows is sorted.
// ---------------------------------------------------------------------------
__global__ void rowptr_kernel(const int* __restrict__ rows, int* __restrict__ rowptr, int nE) {
    int i = blockIdx.x * blockDim.x + threadIdx.x;
    if (i > N_NODES) return;
    int lo = 0, hi = nE;
    while (lo < hi) {
        int mid = (lo + hi) >> 1;
        if (rows[mid] < i) lo = mid + 1; else hi = mid;
    }
    rowptr[i] = lo;
}

// ---------------------------------------------------------------------------
// fc1: h0 = relu(x @ W + b); also writes bf16 copy of h0 for the SpMM gather.
// ---------------------------------------------------------------------------
__global__ void fc1_kernel(const float* __restrict__ x, const float* __restrict__ w,
                           const float* __restrict__ b, float* __restrict__ h0,
                           uint* __restrict__ hb) {
    __shared__ float xs[32][33];
    __shared__ float ws[32][128];
    const int r0 = blockIdx.x * 32;
    const int tid = threadIdx.x;
    const int cg = tid & 31;   // col group -> cols cg*4 .. cg*4+3
    const int rg = tid >> 5;   // row group -> rows rg*4 .. rg*4+3

    float acc[4][4] = {};

    for (int kc = 0; kc < NFEAT; kc += 32) {
        {
            int row = tid >> 3, q = tid & 7;
            float4 v = *reinterpret_cast<const float4*>(x + (r0 + row) * NFEAT + kc + q * 4);
            xs[row][q * 4 + 0] = v.x; xs[row][q * 4 + 1] = v.y;
            xs[row][q * 4 + 2] = v.z; xs[row][q * 4 + 3] = v.w;
        }
        #pragma unroll
        for (int j = 0; j < 4; ++j) {
            int idx = tid + j * 256;
            int kk = idx >> 5, c4 = idx & 31;
            *reinterpret_cast<float4*>(&ws[kk][c4 * 4]) =
                *reinterpret_cast<const float4*>(w + (kc + kk) * NHID + c4 * 4);
        }
        __syncthreads();
        #pragma unroll
        for (int kk = 0; kk < 32; ++kk) {
            float4 bv = *reinterpret_cast<const float4*>(&ws[kk][cg * 4]);
            float av[4];
            #pragma unroll
            for (int m = 0; m < 4; ++m) av[m] = xs[rg * 4 + m][kk];
            #pragma unroll
            for (int m = 0; m < 4; ++m) {
                acc[m][0] = fmaf(av[m], bv.x, acc[m][0]);
                acc[m][1] = fmaf(av[m], bv.y, acc[m][1]);
                acc[m][2] = fmaf(av[m], bv.z, acc[m][2]);
                acc[m][3] = fmaf(av[m], bv.w, acc[m][3]);
            }
        }
        __syncthreads();
    }

    #pragma unroll
    for (int m = 0; m < 4; ++m) {
        int r = r0 + rg * 4 + m;
        int c = cg * 4;
        float4 o;
        o.x = fmaxf(acc[m][0] + b[c + 0], 0.f);
        o.y = fmaxf(acc[m][1] + b[c + 1], 0.f);
        o.z = fmaxf(acc[m][2] + b[c + 2], 0.f);
        o.w = fmaxf(acc[m][3] + b[c + 3], 0.f);
        *reinterpret_cast<float4*>(h0 + r * NHID + c) = o;
        uint2 p; p.x = bf16pack(o.x, o.y); p.y = bf16pack(o.z, o.w);
        *reinterpret_cast<uint2*>(hb + (size_t)r * 64 + cg * 2) = p;
    }
}

// ---------------------------------------------------------------------------
// SpMM + residual mix, latency-optimized:
//   support[n,:] = 0.9 * sum_e vals[e]*h_bf16[cols[e],:] + 0.1*h0[n,:]
// One wave (64 threads) per node, 2 features/lane (bf16x2 gather).
// cols/vals for up to 64 edges loaded coalesced once, broadcast via shfl ->
// the gather is the only in-loop memory op, independent across edges (MLP~16).
// ---------------------------------------------------------------------------
__global__ void spmm_kernel(const uint* __restrict__ hb, const float* __restrict__ h0,
                            const int* __restrict__ rowptr, const int* __restrict__ cols,
                            const float* __restrict__ vals, float* __restrict__ support) {
    const int node = blockIdx.x * 4 + (threadIdx.x >> 6);
    const int lane = threadIdx.x & 63;
    const int e0 = rowptr[node], e1 = rowptr[node + 1];

    float accx = 0.f, accy = 0.f;
    for (int base = e0; base < e1; base += 64) {
        int m = e1 - base; if (m > 64) m = 64;
        int c = 0; float v = 0.f;
        if (lane < m) { c = cols[base + lane]; v = vals[base + lane]; }
        #pragma unroll 4
        for (int j = 0; j < m; ++j) {
            int   cj = __shfl(c, j);
            float vj = __shfl(v, j);
            uint hv = hb[(size_t)cj * 64 + lane];
            float f0 = __uint_as_float(hv << 16);
            float f1 = __uint_as_float(hv & 0xffff0000u);
            accx = fmaf(vj, f0, accx);
            accy = fmaf(vj, f1, accy);
        }
    }

    const int idx = node * NHID + lane * 2;
    const float2 h0v = *reinterpret_cast<const float2*>(h0 + idx);
    float2 o;
    o.x = 0.9f * accx + 0.1f * h0v.x;
    o.y = 0.9f * accy + 0.1f * h0v.y;
    *reinterpret_cast<float2*>(support + idx) = o;
}

// ---------------------------------------------------------------------------
// conv layer GEMM, in place: buf = relu(theta*(buf @ W) + (1-theta)*buf)
// Optionally emits bf16 copy for the next SpMM gather.
// ---------------------------------------------------------------------------
__global__ void layer_kernel(float* __restrict__ buf, const float* __restrict__ w,
                             float theta, uint* __restrict__ hb) {
    __shared__ float as_[32][33];
    __shared__ float ws[32][128];
    const int r0 = blockIdx.x * 32;
    const int tid = threadIdx.x;
    const int cg = tid & 31;
    const int rg = tid >> 5;

    float acc[4][4] = {};

    for (int kc = 0; kc < NHID; kc += 32) {
        {
            int row = tid >> 3, q = tid & 7;
            float4 v = *reinterpret_cast<const float4*>(buf + (r0 + row) * NHID + kc + q * 4);
            as_[row][q * 4 + 0] = v.x; as_[row][q * 4 + 1] = v.y;
            as_[row][q * 4 + 2] = v.z; as_[row][q * 4 + 3] = v.w;
        }
        #pragma unroll
        for (int j = 0; j < 4; ++j) {
            int idx = tid + j * 256;
            int kk = idx >> 5, c4 = idx & 31;
            *reinterpret_cast<float4*>(&ws[kk][c4 * 4]) =
                *reinterpret_cast<const float4*>(w + (kc + kk) * NHID + c4 * 4);
        }
        __syncthreads();
        #pragma unroll
        for (int kk = 0; kk < 32; ++kk) {
            float4 bv = *reinterpret_cast<const float4*>(&ws[kk][cg * 4]);
            float av[4];
            #pragma unroll
            for (int m = 0; m < 4; ++m) av[m] = as_[rg * 4 + m][kk];
            #pragma unroll
            for (int m = 0; m < 4; ++m) {
                acc[m][0] = fmaf(av[m], bv.x, acc[m][0]);
                acc[m][1] = fmaf(av[m], bv.y, acc[m][1]);
                acc[m][2] = fmaf(av[m], bv.z, acc[m][2]);
                acc[m][3] = fmaf(av[m], bv.w, acc[m][3]);
            }
        }
        __syncthreads();
    }

    const float om = 1.f - theta;
    #pragma unroll
    for (int m = 0; m < 4; ++m) {
        int r = r0 + rg * 4 + m;
        int c = cg * 4;
        float4 orig = *reinterpret_cast<const float4*>(buf + r * NHID + c);
        float4 o;
        o.x = fmaxf(fmaf(theta, acc[m][0], om * orig.x), 0.f);
        o.y = fmaxf(fmaf(theta, acc[m][1], om * orig.y), 0.f);
        o.z = fmaxf(fmaf(theta, acc[m][2], om * orig.z), 0.f);
        o.w = fmaxf(fmaf(theta, acc[m][3], om * orig.w), 0.f);
        *reinterpret_cast<float4*>(buf + r * NHID + c) = o;
        if (hb) {
            uint2 p; p.x = bf16pack(o.x, o.y); p.y = bf16pack(o.z, o.w);
            *reinterpret_cast<uint2*>(hb + (size_t)r * 64 + cg * 2) = p;
        }
    }
}

// ---------------------------------------------------------------------------
// final: logits = h @ fc2_w + b; out0 = log_softmax(logits); out2 = [h, logits]
// ---------------------------------------------------------------------------
__global__ void final_kernel(const float* __restrict__ h, const float* __restrict__ w,
                             const float* __restrict__ b, float* __restrict__ out0,
                             float* __restrict__ out2) {
    __shared__ float hs[4][128];
    const int s = threadIdx.x >> 6;
    const int lane = threadIdx.x & 63;
    const int node = blockIdx.x * 4 + s;

    float h_lo = h[node * NHID + lane];
    float h_hi = h[node * NHID + 64 + lane];
    hs[s][lane] = h_lo;
    hs[s][64 + lane] = h_hi;
    __syncthreads();

    float logit = 0.f;
    if (lane < NCLASS) {
        logit = b[lane];
        #pragma unroll 8
        for (int k = 0; k < NHID; ++k)
            logit = fmaf(hs[s][k], w[k * NCLASS + lane], logit);
    }

    float mv = (lane < NCLASS) ? logit : -1e30f;
    #pragma unroll
    for (int m = 32; m; m >>= 1) mv = fmaxf(mv, __shfl_xor(mv, m));
    float ev = (lane < NCLASS) ? __expf(logit - mv) : 0.f;
    float sum = ev;
    #pragma unroll
    for (int m = 32; m; m >>= 1) sum += __shfl_xor(sum, m);
    float lse = mv + __logf(sum);

    if (lane < NCLASS) {
        out0[node * NCLASS + lane] = logit - lse;
        out2[node * 168 + 128 + lane] = logit;
    }
    out2[node * 168 + lane] = h_lo;
    out2[node * 168 + 64 + lane] = h_hi;
}

// ---------------------------------------------------------------------------
extern "C" void kernel_launch(void* const* d_in, const int* in_sizes, int n_in,
                              void* d_out, int out_size, void* d_ws, size_t ws_size,
                              hipStream_t stream) {
    const float* x      = (const float*)d_in[0];
    const int*   rows   = (const int*)  d_in[1];
    const int*   cols   = (const int*)  d_in[2];
    const float* vals   = (const float*)d_in[3];
    const float* fc1_w  = (const float*)d_in[4];
    const float* fc1_b  = (const float*)d_in[5];
    const float* conv_w = (const float*)d_in[6];
    const float* fc2_w  = (const float*)d_in[7];
    const float* fc2_b  = (const float*)d_in[8];
    float* out = (float*)d_out;

    const int nE = in_sizes[1];
    const size_t NH = (size_t)N_NODES * NHID;   // 12.8M floats

    // workspace layout: h0 | bufA | rowptr     (~103 MB)
    float* h0   = (float*)d_ws;
    float* bufA = h0 + NH;
    int*   rowptr = (int*)(bufA + NH);

    // out regions; out1 (final h) doubles as ping-pong buffer B.
    float* out0 = out;                                  // [N,40]
    float* bufB = out + (size_t)N_NODES * NCLASS;       // [N,128] == out1
    float* out2 = bufB + NH;                            // [N,168]
    // bf16 gather copy of current h lives at the head of the out2 region
    // (25.6 MB of 67.2 MB); final_kernel overwrites it at the very end.
    uint* hb = (uint*)out2;

    rowptr_kernel<<<(N_NODES + 1 + 255) / 256, 256, 0, stream>>>(rows, rowptr, nE);
    fc1_kernel<<<N_NODES / 32, 256, 0, stream>>>(x, fc1_w, fc1_b, h0, hb);

    float* bufs[2] = { bufA, bufB };
    for (int i = 0; i < 4; ++i) {
        float* buf = bufs[i & 1];
        float theta = logf(0.5f / (float)(i + 1) + 1.0f);
        spmm_kernel<<<N_NODES / 4, 256, 0, stream>>>(hb, h0, rowptr, cols, vals, buf);
        layer_kernel<<<N_NODES / 32, 256, 0, stream>>>(
            buf, conv_w + (size_t)i * NHID * NHID, theta, (i < 3) ? hb : nullptr);
    }

    // bufB == out1 region: final h already in place.
    final_kernel<<<N_NODES / 4, 256, 0, stream>>>(bufB, fc2_w, fc2_b, out0, out2);
}

// Round 3
// 680.137 us; speedup vs baseline: 2.4043x; 1.3856x over previous
//
#include <hip/hip_runtime.h>
#include <math.h>

#define N_NODES 100000
#define NFEAT 512
#define NHID 128
#define NCLASS 40

typedef unsigned int uint;
typedef unsigned short ushort;
typedef short bf16x8 __attribute__((ext_vector_type(8)));
typedef float f32x4 __attribute__((ext_vector_type(4)));

// f32 -> bf16 (RNE)
__device__ inline ushort bf16s(float a) {
    uint u = __float_as_uint(a);
    return (ushort)((u + 0x7fffu + ((u >> 16) & 1u)) >> 16);
}
__device__ inline uint bf16pack(float a, float b) {
    return (uint)bf16s(a) | ((uint)bf16s(b) << 16);
}
__device__ inline float bf16tof(ushort u) { return __uint_as_float(((uint)u) << 16); }

// ---------------------------------------------------------------------------
// weight prep: wT1[n][k] = bf16(fc1_w[k][n])   (128 x 512)
//              wTc[L][n][k] = bf16(conv_w[L][k][n])  (4 x 128 x 128)
// ---------------------------------------------------------------------------
__global__ void prep_weights(const float* __restrict__ fc1_w, const float* __restrict__ conv_w,
                             ushort* __restrict__ wT1, ushort* __restrict__ wTc) {
    int idx = blockIdx.x * 256 + threadIdx.x;   // 65536 total
    {   int n = idx >> 9, k = idx & 511;
        wT1[idx] = bf16s(fc1_w[k * NHID + n]); }
    {   int L = idx >> 14, rem = idx & 16383;
        int n = rem >> 7, k = rem & 127;
        wTc[idx] = bf16s(conv_w[L * 16384 + k * NHID + n]); }
}

// ---------------------------------------------------------------------------
// row_ptr[i] = lower_bound(rows, i)
// ---------------------------------------------------------------------------
__global__ void rowptr_kernel(const int* __restrict__ rows, int* __restrict__ rowptr, int nE) {
    int i = blockIdx.x * blockDim.x + threadIdx.x;
    if (i > N_NODES) return;
    int lo = 0, hi = nE;
    while (lo < hi) { int mid = (lo + hi) >> 1; if (rows[mid] < i) lo = mid + 1; else hi = mid; }
    rowptr[i] = lo;
}

// ---------------------------------------------------------------------------
// fc1 MFMA: h0b = bf16(relu(x @ W + b)). BM=32, BN=128, K=512 (16 steps of 32).
// 4 waves: (wr,wc) in 2x2, each wave 16 rows x 64 cols = 4 accum frags.
// ---------------------------------------------------------------------------
__global__ void __launch_bounds__(256) fc1_mfma(const float* __restrict__ x,
                                                const uint* __restrict__ wT1,
                                                const float* __restrict__ bias,
                                                ushort* __restrict__ h0b) {
    __shared__ ushort As[32][40];    // row stride 80B -> 2-way bank alias (free)
    __shared__ ushort Bs[128][40];   // Bs[n][k-slice], transposed weights
    const int tid = threadIdx.x;
    const int lane = tid & 63;
    const int wave = tid >> 6;
    const int wr = wave >> 1, wc = wave & 1;
    const int r0 = blockIdx.x * 32;

    f32x4 acc[4] = {};

    for (int ks = 0; ks < NFEAT; ks += 32) {
        {   // stage A (32x32 f32 -> bf16)
            int row = tid >> 3, c4 = tid & 7;
            float4 v = *reinterpret_cast<const float4*>(x + (size_t)(r0 + row) * NFEAT + ks + c4 * 4);
            uint2 p; p.x = bf16pack(v.x, v.y); p.y = bf16pack(v.z, v.w);
            *reinterpret_cast<uint2*>(&As[row][c4 * 4]) = p;
        }
        {   // stage B slice (128 n x 32 k bf16)
            #pragma unroll
            for (int p = 0; p < 2; ++p) {
                int idx = tid + p * 256;
                int n = idx >> 2, kq = idx & 3;
                uint4 v = *reinterpret_cast<const uint4*>(wT1 + n * 256 + (ks >> 1) + kq * 4);
                *reinterpret_cast<uint4*>(&Bs[n][kq * 8]) = v;
            }
        }
        __syncthreads();
        bf16x8 a = *reinterpret_cast<const bf16x8*>(&As[wr * 16 + (lane & 15)][(lane >> 4) * 8]);
        #pragma unroll
        for (int j = 0; j < 4; ++j) {
            bf16x8 b = *reinterpret_cast<const bf16x8*>(&Bs[wc * 64 + j * 16 + (lane & 15)][(lane >> 4) * 8]);
            acc[j] = __builtin_amdgcn_mfma_f32_16x16x32_bf16(a, b, acc[j], 0, 0, 0);
        }
        __syncthreads();
    }

    const int cb = wc * 64 + (lane & 15);
    const int rb = r0 + wr * 16 + ((lane >> 4) << 2);
    #pragma unroll
    for (int j = 0; j < 4; ++j) {
        int col = cb + j * 16;
        float bj = bias[col];
        #pragma unroll
        for (int i = 0; i < 4; ++i) {
            float v = fmaxf(acc[j][i] + bj, 0.f);
            h0b[(size_t)(rb + i) * NHID + col] = bf16s(v);
        }
    }
}

// ---------------------------------------------------------------------------
// conv layer MFMA: out = relu(theta*(S @ W) + (1-theta)*S), S = sb (bf16).
// BM=32, K=128 staged fully -> one barrier, 4 K-steps of pure ds_read+MFMA.
// Residual S re-read from LDS. Writes hb (bf16) or fout (f32, last layer).
// ---------------------------------------------------------------------------
__global__ void __launch_bounds__(256) layer_mfma(const uint* __restrict__ sb,
                                                  const uint* __restrict__ wTc,
                                                  float theta,
                                                  ushort* __restrict__ hb,
                                                  float* __restrict__ fout) {
    __shared__ ushort As[32][136];    // row stride 272B
    __shared__ ushort Bs[128][136];
    const int tid = threadIdx.x;
    const int lane = tid & 63;
    const int wave = tid >> 6;
    const int wr = wave >> 1, wc = wave & 1;
    const int r0 = blockIdx.x * 32;

    #pragma unroll
    for (int p = 0; p < 2; ++p) {   // stage A: 32 rows x 128 k
        int idx = tid + p * 256;
        int row = idx >> 4, kq = idx & 15;
        uint4 v = *reinterpret_cast<const uint4*>(sb + (size_t)(r0 + row) * 64 + kq * 4);
        *reinterpret_cast<uint4*>(&As[row][kq * 8]) = v;
    }
    #pragma unroll
    for (int p = 0; p < 8; ++p) {   // stage B: 128 n x 128 k
        int idx = tid + p * 256;
        int n = idx >> 4, kq = idx & 15;
        uint4 v = *reinterpret_cast<const uint4*>(wTc + n * 64 + kq * 4);
        *reinterpret_cast<uint4*>(&Bs[n][kq * 8]) = v;
    }
    __syncthreads();

    f32x4 acc[4] = {};
    #pragma unroll
    for (int ks = 0; ks < NHID; ks += 32) {
        bf16x8 a = *reinterpret_cast<const bf16x8*>(&As[wr * 16 + (lane & 15)][ks + (lane >> 4) * 8]);
        #pragma unroll
        for (int j = 0; j < 4; ++j) {
            bf16x8 b = *reinterpret_cast<const bf16x8*>(&Bs[wc * 64 + j * 16 + (lane & 15)][ks + (lane >> 4) * 8]);
            acc[j] = __builtin_amdgcn_mfma_f32_16x16x32_bf16(a, b, acc[j], 0, 0, 0);
        }
    }

    const float om = 1.f - theta;
    const int cb = wc * 64 + (lane & 15);
    const int rloc = wr * 16 + ((lane >> 4) << 2);
    #pragma unroll
    for (int j = 0; j < 4; ++j) {
        int col = cb + j * 16;
        #pragma unroll
        for (int i = 0; i < 4; ++i) {
            float s = bf16tof(As[rloc + i][col]);
            float v = fmaxf(fmaf(theta, acc[j][i], om * s), 0.f);
            if (fout) fout[(size_t)(r0 + rloc + i) * NHID + col] = v;
            else      hb[(size_t)(r0 + rloc + i) * NHID + col] = bf16s(v);
        }
    }
}

// ---------------------------------------------------------------------------
// SpMM + residual: sb[n,:] = bf16(0.9 * sum_e vals[e]*hb[cols[e],:] + 0.1*h0b[n,:])
// One wave per node, 2 features/lane (bf16x2), shfl-broadcast cols/vals.
// ---------------------------------------------------------------------------
__global__ void spmm_kernel(const uint* __restrict__ hb, const uint* __restrict__ h0b,
                            const int* __restrict__ rowptr, const int* __restrict__ cols,
                            const float* __restrict__ vals, uint* __restrict__ sb) {
    const int node = blockIdx.x * 4 + (threadIdx.x >> 6);
    const int lane = threadIdx.x & 63;
    const int e0 = rowptr[node], e1 = rowptr[node + 1];

    float accx = 0.f, accy = 0.f;
    for (int base = e0; base < e1; base += 64) {
        int m = e1 - base; if (m > 64) m = 64;
        int c = 0; float v = 0.f;
        if (lane < m) { c = cols[base + lane]; v = vals[base + lane]; }
        #pragma unroll 4
        for (int j = 0; j < m; ++j) {
            int   cj = __shfl(c, j);
            float vj = __shfl(v, j);
            uint hv = hb[(size_t)cj * 64 + lane];
            accx = fmaf(vj, __uint_as_float(hv << 16), accx);
            accy = fmaf(vj, __uint_as_float(hv & 0xffff0000u), accy);
        }
    }

    uint h0v = h0b[(size_t)node * 64 + lane];
    float ox = 0.9f * accx + 0.1f * __uint_as_float(h0v << 16);
    float oy = 0.9f * accy + 0.1f * __uint_as_float(h0v & 0xffff0000u);
    sb[(size_t)node * 64 + lane] = bf16pack(ox, oy);
}

// ---------------------------------------------------------------------------
// final: logits = h @ fc2_w + b; out0 = log_softmax; out2 = [h, logits]
// ---------------------------------------------------------------------------
__global__ void final_kernel(const float* __restrict__ h, const float* __restrict__ w,
                             const float* __restrict__ b, float* __restrict__ out0,
                             float* __restrict__ out2) {
    __shared__ float hs[4][128];
    const int s = threadIdx.x >> 6;
    const int lane = threadIdx.x & 63;
    const int node = blockIdx.x * 4 + s;

    float h_lo = h[node * NHID + lane];
    float h_hi = h[node * NHID + 64 + lane];
    hs[s][lane] = h_lo;
    hs[s][64 + lane] = h_hi;
    __syncthreads();

    float logit = 0.f;
    if (lane < NCLASS) {
        logit = b[lane];
        #pragma unroll 8
        for (int k = 0; k < NHID; ++k)
            logit = fmaf(hs[s][k], w[k * NCLASS + lane], logit);
    }

    float mv = (lane < NCLASS) ? logit : -1e30f;
    #pragma unroll
    for (int m = 32; m; m >>= 1) mv = fmaxf(mv, __shfl_xor(mv, m));
    float ev = (lane < NCLASS) ? __expf(logit - mv) : 0.f;
    float sum = ev;
    #pragma unroll
    for (int m = 32; m; m >>= 1) sum += __shfl_xor(sum, m);
    float lse = mv + __logf(sum);

    if (lane < NCLASS) {
        out0[node * NCLASS + lane] = logit - lse;
        out2[node * 168 + 128 + lane] = logit;
    }
    out2[node * 168 + lane] = h_lo;
    out2[node * 168 + 64 + lane] = h_hi;
}

// ---------------------------------------------------------------------------
extern "C" void kernel_launch(void* const* d_in, const int* in_sizes, int n_in,
                              void* d_out, int out_size, void* d_ws, size_t ws_size,
                              hipStream_t stream) {
    const float* x      = (const float*)d_in[0];
    const int*   rows   = (const int*)  d_in[1];
    const int*   cols   = (const int*)  d_in[2];
    const float* vals   = (const float*)d_in[3];
    const float* fc1_w  = (const float*)d_in[4];
    const float* fc1_b  = (const float*)d_in[5];
    const float* conv_w = (const float*)d_in[6];
    const float* fc2_w  = (const float*)d_in[7];
    const float* fc2_b  = (const float*)d_in[8];
    float* out = (float*)d_out;

    const int nE = in_sizes[1];
    const size_t NH = (size_t)N_NODES * NHID;   // 12.8M elements

    // workspace layout
    char* p = (char*)d_ws;
    int*    rowptr = (int*)p;          p += 400128;          // 100001 ints, padded
    ushort* h0b    = (ushort*)p;       p += NH * 2;          // 25.6 MB
    ushort* hb     = (ushort*)p;       p += NH * 2;          // 25.6 MB
    ushort* sb     = (ushort*)p;       p += NH * 2;          // 25.6 MB
    ushort* wT1    = (ushort*)p;       p += 65536 * 2;       // 128 KB
    ushort* wTc    = (ushort*)p;       p += 65536 * 2;       // 128 KB

    // out regions
    float* out0 = out;                                  // [N,40]
    float* out1 = out + (size_t)N_NODES * NCLASS;       // [N,128] final h (f32)
    float* out2 = out1 + NH;                            // [N,168]

    prep_weights<<<256, 256, 0, stream>>>(fc1_w, conv_w, wT1, wTc);
    rowptr_kernel<<<(N_NODES + 1 + 255) / 256, 256, 0, stream>>>(rows, rowptr, nE);
    fc1_mfma<<<N_NODES / 32, 256, 0, stream>>>(x, (const uint*)wT1, fc1_b, h0b);

    for (int i = 0; i < 4; ++i) {
        float theta = logf(0.5f / (float)(i + 1) + 1.0f);
        spmm_kernel<<<N_NODES / 4, 256, 0, stream>>>(
            (const uint*)(i == 0 ? h0b : hb), (const uint*)h0b, rowptr, cols, vals, (uint*)sb);
        layer_mfma<<<N_NODES / 32, 256, 0, stream>>>(
            (const uint*)sb, (const uint*)(wTc + (size_t)i * 16384), theta,
            (i < 3) ? hb : nullptr, (i == 3) ? out1 : nullptr);
    }

    final_kernel<<<N_NODES / 4, 256, 0, stream>>>(out1, fc2_w, fc2_b, out0, out2);
}

// Round 4
// 543.701 us; speedup vs baseline: 3.0077x; 1.2509x over previous
//
#include <hip/hip_runtime.h>
#include <math.h>

#define N_NODES 100000
#define NFEAT 512
#define NHID 128
#define NCLASS 40

typedef unsigned int uint;
typedef unsigned short ushort;
typedef short bf16x8 __attribute__((ext_vector_type(8)));
typedef float f32x4 __attribute__((ext_vector_type(4)));

// f32 -> bf16 (RNE)
__device__ inline ushort bf16s(float a) {
    uint u = __float_as_uint(a);
    return (ushort)((u + 0x7fffu + ((u >> 16) & 1u)) >> 16);
}
__device__ inline uint bf16pack(float a, float b) {
    return (uint)bf16s(a) | ((uint)bf16s(b) << 16);
}
__device__ inline float bf16tof(ushort u) { return __uint_as_float(((uint)u) << 16); }
__device__ inline float bflo(uint u) { return __uint_as_float(u << 16); }
__device__ inline float bfhi(uint u) { return __uint_as_float(u & 0xffff0000u); }

// ---------------------------------------------------------------------------
// weight prep: wT1[n][k] = bf16(fc1_w[k][n])   (128 x 512)
//              wTc[L][n][k] = bf16(conv_w[L][k][n])  (4 x 128 x 128)
// ---------------------------------------------------------------------------
__global__ void prep_weights(const float* __restrict__ fc1_w, const float* __restrict__ conv_w,
                             ushort* __restrict__ wT1, ushort* __restrict__ wTc) {
    int idx = blockIdx.x * 256 + threadIdx.x;   // 65536 total
    {   int n = idx >> 9, k = idx & 511;
        wT1[idx] = bf16s(fc1_w[k * NHID + n]); }
    {   int L = idx >> 14, rem = idx & 16383;
        int n = rem >> 7, k = rem & 127;
        wTc[idx] = bf16s(conv_w[L * 16384 + k * NHID + n]); }
}

// ---------------------------------------------------------------------------
// row_ptr[i] = lower_bound(rows, i)
// ---------------------------------------------------------------------------
__global__ void rowptr_kernel(const int* __restrict__ rows, int* __restrict__ rowptr, int nE) {
    int i = blockIdx.x * blockDim.x + threadIdx.x;
    if (i > N_NODES) return;
    int lo = 0, hi = nE;
    while (lo < hi) { int mid = (lo + hi) >> 1; if (rows[mid] < i) lo = mid + 1; else hi = mid; }
    rowptr[i] = lo;
}

// ---------------------------------------------------------------------------
// fc1 MFMA: h0b = bf16(relu(x @ W + b)). BM=32, BN=128, K=512, K-step 64.
// 4 waves: (wr,wc) in 2x2, each wave 16 rows x 64 cols.
// ---------------------------------------------------------------------------
__global__ void __launch_bounds__(256) fc1_mfma(const float* __restrict__ x,
                                                const uint* __restrict__ wT1,
                                                const float* __restrict__ bias,
                                                ushort* __restrict__ h0b) {
    __shared__ ushort As[32][72];    // row stride 144B -> 2-way alias (free)
    __shared__ ushort Bs[128][72];
    const int tid = threadIdx.x;
    const int lane = tid & 63;
    const int wave = tid >> 6;
    const int wr = wave >> 1, wc = wave & 1;
    const int r0 = blockIdx.x * 32;

    f32x4 acc[4] = {};

    for (int ks = 0; ks < NFEAT; ks += 64) {
        {   // stage A: 32 rows x 64 k, f32 -> bf16, 8 k-values per thread
            int row = tid >> 3, kq = tid & 7;
            const float* xp = x + (size_t)(r0 + row) * NFEAT + ks + kq * 8;
            float4 v0 = *reinterpret_cast<const float4*>(xp);
            float4 v1 = *reinterpret_cast<const float4*>(xp + 4);
            uint4 pk;
            pk.x = bf16pack(v0.x, v0.y); pk.y = bf16pack(v0.z, v0.w);
            pk.z = bf16pack(v1.x, v1.y); pk.w = bf16pack(v1.z, v1.w);
            *reinterpret_cast<uint4*>(&As[row][kq * 8]) = pk;
        }
        #pragma unroll
        for (int p = 0; p < 4; ++p) {   // stage B: 128 n x 64 k
            int idx = tid + p * 256;
            int n = idx >> 3, q = idx & 7;
            uint4 w4 = *reinterpret_cast<const uint4*>(wT1 + n * 256 + (ks >> 1) + q * 4);
            *reinterpret_cast<uint4*>(&Bs[n][q * 8]) = w4;
        }
        __syncthreads();
        #pragma unroll
        for (int ks2 = 0; ks2 < 64; ks2 += 32) {
            bf16x8 a = *reinterpret_cast<const bf16x8*>(&As[wr * 16 + (lane & 15)][ks2 + (lane >> 4) * 8]);
            #pragma unroll
            for (int j = 0; j < 4; ++j) {
                bf16x8 b = *reinterpret_cast<const bf16x8*>(&Bs[wc * 64 + j * 16 + (lane & 15)][ks2 + (lane >> 4) * 8]);
                acc[j] = __builtin_amdgcn_mfma_f32_16x16x32_bf16(a, b, acc[j], 0, 0, 0);
            }
        }
        __syncthreads();
    }

    const int cb = wc * 64 + (lane & 15);
    const int rb = r0 + wr * 16 + ((lane >> 4) << 2);
    #pragma unroll
    for (int j = 0; j < 4; ++j) {
        int col = cb + j * 16;
        float bj = bias[col];
        #pragma unroll
        for (int i = 0; i < 4; ++i) {
            float v = fmaxf(acc[j][i] + bj, 0.f);
            h0b[(size_t)(rb + i) * NHID + col] = bf16s(v);
        }
    }
}

// ---------------------------------------------------------------------------
// conv layer MFMA: out = relu(theta*(S @ W) + (1-theta)*S), S = sb (bf16).
// ---------------------------------------------------------------------------
__global__ void __launch_bounds__(256) layer_mfma(const uint* __restrict__ sb,
                                                  const uint* __restrict__ wTc,
                                                  float theta,
                                                  ushort* __restrict__ hb,
                                                  float* __restrict__ fout) {
    __shared__ ushort As[32][136];
    __shared__ ushort Bs[128][136];
    const int tid = threadIdx.x;
    const int lane = tid & 63;
    const int wave = tid >> 6;
    const int wr = wave >> 1, wc = wave & 1;
    const int r0 = blockIdx.x * 32;

    #pragma unroll
    for (int p = 0; p < 2; ++p) {   // stage A: 32 rows x 128 k
        int idx = tid + p * 256;
        int row = idx >> 4, kq = idx & 15;
        uint4 v = *reinterpret_cast<const uint4*>(sb + (size_t)(r0 + row) * 64 + kq * 4);
        *reinterpret_cast<uint4*>(&As[row][kq * 8]) = v;
    }
    #pragma unroll
    for (int p = 0; p < 8; ++p) {   // stage B: 128 n x 128 k
        int idx = tid + p * 256;
        int n = idx >> 4, kq = idx & 15;
        uint4 v = *reinterpret_cast<const uint4*>(wTc + n * 64 + kq * 4);
        *reinterpret_cast<uint4*>(&Bs[n][kq * 8]) = v;
    }
    __syncthreads();

    f32x4 acc[4] = {};
    #pragma unroll
    for (int ks = 0; ks < NHID; ks += 32) {
        bf16x8 a = *reinterpret_cast<const bf16x8*>(&As[wr * 16 + (lane & 15)][ks + (lane >> 4) * 8]);
        #pragma unroll
        for (int j = 0; j < 4; ++j) {
            bf16x8 b = *reinterpret_cast<const bf16x8*>(&Bs[wc * 64 + j * 16 + (lane & 15)][ks + (lane >> 4) * 8]);
            acc[j] = __builtin_amdgcn_mfma_f32_16x16x32_bf16(a, b, acc[j], 0, 0, 0);
        }
    }

    const float om = 1.f - theta;
    const int cb = wc * 64 + (lane & 15);
    const int rloc = wr * 16 + ((lane >> 4) << 2);
    #pragma unroll
    for (int j = 0; j < 4; ++j) {
        int col = cb + j * 16;
        #pragma unroll
        for (int i = 0; i < 4; ++i) {
            float s = bf16tof(As[rloc + i][col]);
            float v = fmaxf(fmaf(theta, acc[j][i], om * s), 0.f);
            if (fout) fout[(size_t)(r0 + rloc + i) * NHID + col] = v;
            else      hb[(size_t)(r0 + rloc + i) * NHID + col] = bf16s(v);
        }
    }
}

// ---------------------------------------------------------------------------
// SpMM + residual: sb[n,:] = bf16(0.9 * sum_e vals[e]*hb[cols[e],:] + 0.1*h0b[n,:])
// One wave per node. Two 32-lane halves process alternating edges; each half
// reads a full 256B row as uint2/lane -> 2 edges in flight per issue slot,
// unroll 8 -> up to 8 independent gathers outstanding per wave.
// ---------------------------------------------------------------------------
__global__ void spmm_kernel(const uint2* __restrict__ hb2, const uint2* __restrict__ h0b2,
                            const int* __restrict__ rowptr, const int* __restrict__ cols,
                            const float* __restrict__ vals, uint2* __restrict__ sb2) {
    const int node = blockIdx.x * 4 + (threadIdx.x >> 6);
    const int lane = threadIdx.x & 63;
    const int half = lane >> 5;       // which edge-parity this lane handles
    const int l    = lane & 31;       // feature quad: features 4l..4l+3

    const int e0 = rowptr[node], e1 = rowptr[node + 1];

    float a0 = 0.f, a1 = 0.f, a2 = 0.f, a3 = 0.f;
    for (int base = e0; base < e1; base += 64) {
        int m = e1 - base; if (m > 64) m = 64;
        int c = 0; float v = 0.f;
        if (lane < m) { c = cols[base + lane]; v = vals[base + lane]; }
        const int nt = (m + 1) >> 1;
        #pragma unroll 8
        for (int t = 0; t < nt; ++t) {
            int j = 2 * t + half;
            int jc = (j < m) ? j : 0;
            int   cj = __shfl(c, jc);
            float vj = __shfl(v, jc);
            if (j >= m) vj = 0.f;
            uint2 hv = hb2[(size_t)cj * 32 + l];
            a0 = fmaf(vj, bflo(hv.x), a0);
            a1 = fmaf(vj, bfhi(hv.x), a1);
            a2 = fmaf(vj, bflo(hv.y), a2);
            a3 = fmaf(vj, bfhi(hv.y), a3);
        }
    }
    // combine the two halves
    a0 += __shfl_xor(a0, 32);
    a1 += __shfl_xor(a1, 32);
    a2 += __shfl_xor(a2, 32);
    a3 += __shfl_xor(a3, 32);

    if (half == 0) {
        uint2 h0v = h0b2[(size_t)node * 32 + l];
        float o0 = 0.9f * a0 + 0.1f * bflo(h0v.x);
        float o1 = 0.9f * a1 + 0.1f * bfhi(h0v.x);
        float o2 = 0.9f * a2 + 0.1f * bflo(h0v.y);
        float o3 = 0.9f * a3 + 0.1f * bfhi(h0v.y);
        uint2 o; o.x = bf16pack(o0, o1); o.y = bf16pack(o2, o3);
        sb2[(size_t)node * 32 + l] = o;
    }
}

// ---------------------------------------------------------------------------
// final: logits = h @ fc2_w + b; out0 = log_softmax; out2 = [h, logits]
// ---------------------------------------------------------------------------
__global__ void final_kernel(const float* __restrict__ h, const float* __restrict__ w,
                             const float* __restrict__ b, float* __restrict__ out0,
                             float* __restrict__ out2) {
    __shared__ float hs[4][128];
    const int s = threadIdx.x >> 6;
    const int lane = threadIdx.x & 63;
    const int node = blockIdx.x * 4 + s;

    float h_lo = h[node * NHID + lane];
    float h_hi = h[node * NHID + 64 + lane];
    hs[s][lane] = h_lo;
    hs[s][64 + lane] = h_hi;
    __syncthreads();

    float logit = 0.f;
    if (lane < NCLASS) {
        logit = b[lane];
        #pragma unroll 8
        for (int k = 0; k < NHID; ++k)
            logit = fmaf(hs[s][k], w[k * NCLASS + lane], logit);
    }

    float mv = (lane < NCLASS) ? logit : -1e30f;
    #pragma unroll
    for (int m = 32; m; m >>= 1) mv = fmaxf(mv, __shfl_xor(mv, m));
    float ev = (lane < NCLASS) ? __expf(logit - mv) : 0.f;
    float sum = ev;
    #pragma unroll
    for (int m = 32; m; m >>= 1) sum += __shfl_xor(sum, m);
    float lse = mv + __logf(sum);

    if (lane < NCLASS) {
        out0[node * NCLASS + lane] = logit - lse;
        out2[node * 168 + 128 + lane] = logit;
    }
    out2[node * 168 + lane] = h_lo;
    out2[node * 168 + 64 + lane] = h_hi;
}

// ---------------------------------------------------------------------------
extern "C" void kernel_launch(void* const* d_in, const int* in_sizes, int n_in,
                              void* d_out, int out_size, void* d_ws, size_t ws_size,
                              hipStream_t stream) {
    const float* x      = (const float*)d_in[0];
    const int*   rows   = (const int*)  d_in[1];
    const int*   cols   = (const int*)  d_in[2];
    const float* vals   = (const float*)d_in[3];
    const float* fc1_w  = (const float*)d_in[4];
    const float* fc1_b  = (const float*)d_in[5];
    const float* conv_w = (const float*)d_in[6];
    const float* fc2_w  = (const float*)d_in[7];
    const float* fc2_b  = (const float*)d_in[8];
    float* out = (float*)d_out;

    const int nE = in_sizes[1];
    const size_t NH = (size_t)N_NODES * NHID;   // 12.8M elements

    // workspace layout
    char* p = (char*)d_ws;
    int*    rowptr = (int*)p;          p += 400128;          // 100001 ints, padded
    ushort* h0b    = (ushort*)p;       p += NH * 2;          // 25.6 MB
    ushort* hb     = (ushort*)p;       p += NH * 2;          // 25.6 MB
    ushort* sb     = (ushort*)p;       p += NH * 2;          // 25.6 MB
    ushort* wT1    = (ushort*)p;       p += 65536 * 2;       // 128 KB
    ushort* wTc    = (ushort*)p;       p += 65536 * 2;       // 128 KB

    // out regions
    float* out0 = out;                                  // [N,40]
    float* out1 = out + (size_t)N_NODES * NCLASS;       // [N,128] final h (f32)
    float* out2 = out1 + NH;                            // [N,168]

    prep_weights<<<256, 256, 0, stream>>>(fc1_w, conv_w, wT1, wTc);
    rowptr_kernel<<<(N_NODES + 1 + 255) / 256, 256, 0, stream>>>(rows, rowptr, nE);
    fc1_mfma<<<N_NODES / 32, 256, 0, stream>>>(x, (const uint*)wT1, fc1_b, h0b);

    for (int i = 0; i < 4; ++i) {
        float theta = logf(0.5f / (float)(i + 1) + 1.0f);
        spmm_kernel<<<N_NODES / 4, 256, 0, stream>>>(
            (const uint2*)(i == 0 ? h0b : hb), (const uint2*)h0b, rowptr, cols, vals, (uint2*)sb);
        layer_mfma<<<N_NODES / 32, 256, 0, stream>>>(
            (const uint*)sb, (const uint*)(wTc + (size_t)i * 16384), theta,
            (i < 3) ? hb : nullptr, (i == 3) ? out1 : nullptr);
    }

    final_kernel<<<N_NODES / 4, 256, 0, stream>>>(out1, fc2_w, fc2_b, out0, out2);
}

// Round 5
// 501.165 us; speedup vs baseline: 3.2630x; 1.0849x over previous
//
#include <hip/hip_runtime.h>
#include <math.h>

#define N_NODES 100000
#define NFEAT 512
#define NHID 128
#define NCLASS 40

typedef unsigned int uint;
typedef unsigned short ushort;
typedef short bf16x8 __attribute__((ext_vector_type(8)));
typedef float f32x4 __attribute__((ext_vector_type(4)));

// f32 -> bf16 (RNE)
__device__ inline ushort bf16s(float a) {
    uint u = __float_as_uint(a);
    return (ushort)((u + 0x7fffu + ((u >> 16) & 1u)) >> 16);
}
__device__ inline uint bf16pack(float a, float b) {
    return (uint)bf16s(a) | ((uint)bf16s(b) << 16);
}
__device__ inline float bf16tof(ushort u) { return __uint_as_float(((uint)u) << 16); }
__device__ inline float bflo(uint u) { return __uint_as_float(u << 16); }
__device__ inline float bfhi(uint u) { return __uint_as_float(u & 0xffff0000u); }

// ---------------------------------------------------------------------------
// weight prep: wT1[n][k] = bf16(fc1_w[k][n])   (128 x 512)
//              wTc[L][n][k] = bf16(conv_w[L][k][n])  (4 x 128 x 128)
// ---------------------------------------------------------------------------
__global__ void prep_weights(const float* __restrict__ fc1_w, const float* __restrict__ conv_w,
                             ushort* __restrict__ wT1, ushort* __restrict__ wTc) {
    int idx = blockIdx.x * 256 + threadIdx.x;   // 65536 total
    {   int n = idx >> 9, k = idx & 511;
        wT1[idx] = bf16s(fc1_w[k * NHID + n]); }
    {   int L = idx >> 14, rem = idx & 16383;
        int n = rem >> 7, k = rem & 127;
        wTc[idx] = bf16s(conv_w[L * 16384 + k * NHID + n]); }
}

// ---------------------------------------------------------------------------
// row_ptr[i] = lower_bound(rows, i)
// ---------------------------------------------------------------------------
__global__ void rowptr_kernel(const int* __restrict__ rows, int* __restrict__ rowptr, int nE) {
    int i = blockIdx.x * blockDim.x + threadIdx.x;
    if (i > N_NODES) return;
    int lo = 0, hi = nE;
    while (lo < hi) { int mid = (lo + hi) >> 1; if (rows[mid] < i) lo = mid + 1; else hi = mid; }
    rowptr[i] = lo;
}

// ---------------------------------------------------------------------------
// fc1 MFMA: h0b = bf16(relu(x @ W + b)). BM=32, BN=128, K=512, K-step 64.
// ---------------------------------------------------------------------------
__global__ void __launch_bounds__(256) fc1_mfma(const float* __restrict__ x,
                                                const uint* __restrict__ wT1,
                                                const float* __restrict__ bias,
                                                ushort* __restrict__ h0b) {
    __shared__ ushort As[32][72];
    __shared__ ushort Bs[128][72];
    const int tid = threadIdx.x;
    const int lane = tid & 63;
    const int wave = tid >> 6;
    const int wr = wave >> 1, wc = wave & 1;
    const int r0 = blockIdx.x * 32;

    f32x4 acc[4] = {};

    for (int ks = 0; ks < NFEAT; ks += 64) {
        {   int row = tid >> 3, kq = tid & 7;
            const float* xp = x + (size_t)(r0 + row) * NFEAT + ks + kq * 8;
            float4 v0 = *reinterpret_cast<const float4*>(xp);
            float4 v1 = *reinterpret_cast<const float4*>(xp + 4);
            uint4 pk;
            pk.x = bf16pack(v0.x, v0.y); pk.y = bf16pack(v0.z, v0.w);
            pk.z = bf16pack(v1.x, v1.y); pk.w = bf16pack(v1.z, v1.w);
            *reinterpret_cast<uint4*>(&As[row][kq * 8]) = pk;
        }
        #pragma unroll
        for (int p = 0; p < 4; ++p) {
            int idx = tid + p * 256;
            int n = idx >> 3, q = idx & 7;
            uint4 w4 = *reinterpret_cast<const uint4*>(wT1 + n * 256 + (ks >> 1) + q * 4);
            *reinterpret_cast<uint4*>(&Bs[n][q * 8]) = w4;
        }
        __syncthreads();
        #pragma unroll
        for (int ks2 = 0; ks2 < 64; ks2 += 32) {
            bf16x8 a = *reinterpret_cast<const bf16x8*>(&As[wr * 16 + (lane & 15)][ks2 + (lane >> 4) * 8]);
            #pragma unroll
            for (int j = 0; j < 4; ++j) {
                bf16x8 b = *reinterpret_cast<const bf16x8*>(&Bs[wc * 64 + j * 16 + (lane & 15)][ks2 + (lane >> 4) * 8]);
                acc[j] = __builtin_amdgcn_mfma_f32_16x16x32_bf16(a, b, acc[j], 0, 0, 0);
            }
        }
        __syncthreads();
    }

    const int cb = wc * 64 + (lane & 15);
    const int rb = r0 + wr * 16 + ((lane >> 4) << 2);
    #pragma unroll
    for (int j = 0; j < 4; ++j) {
        int col = cb + j * 16;
        float bj = bias[col];
        #pragma unroll
        for (int i = 0; i < 4; ++i) {
            float v = fmaxf(acc[j][i] + bj, 0.f);
            h0b[(size_t)(rb + i) * NHID + col] = bf16s(v);
        }
    }
}

// ---------------------------------------------------------------------------
// conv layer MFMA, BM=64: out = relu(theta*(S @ W) + (1-theta)*S).
// 4 waves in 2x2; each wave 32 rows x 64 cols (acc[2][4]).
// sb is padded by 64 rows so tail-block A-staging reads stay in bounds;
// stores are guarded at N_NODES.
// ---------------------------------------------------------------------------
__global__ void __launch_bounds__(256) layer_mfma(const uint* __restrict__ sb,
                                                  const uint* __restrict__ wTc,
                                                  float theta,
                                                  ushort* __restrict__ hb,
                                                  float* __restrict__ fout) {
    __shared__ ushort As[64][136];
    __shared__ ushort Bs[128][136];
    const int tid = threadIdx.x;
    const int lane = tid & 63;
    const int wave = tid >> 6;
    const int wr = wave >> 1, wc = wave & 1;
    const int r0 = blockIdx.x * 64;

    #pragma unroll
    for (int p = 0; p < 4; ++p) {   // stage A: 64 rows x 128 k
        int idx = tid + p * 256;
        int row = idx >> 4, kq = idx & 15;
        uint4 v = *reinterpret_cast<const uint4*>(sb + (size_t)(r0 + row) * 64 + kq * 4);
        *reinterpret_cast<uint4*>(&As[row][kq * 8]) = v;
    }
    #pragma unroll
    for (int p = 0; p < 8; ++p) {   // stage B: 128 n x 128 k
        int idx = tid + p * 256;
        int n = idx >> 4, kq = idx & 15;
        uint4 v = *reinterpret_cast<const uint4*>(wTc + n * 64 + kq * 4);
        *reinterpret_cast<uint4*>(&Bs[n][kq * 8]) = v;
    }
    __syncthreads();

    f32x4 acc[2][4] = {};
    #pragma unroll
    for (int ks = 0; ks < NHID; ks += 32) {
        #pragma unroll
        for (int mr = 0; mr < 2; ++mr) {
            bf16x8 a = *reinterpret_cast<const bf16x8*>(&As[wr * 32 + mr * 16 + (lane & 15)][ks + (lane >> 4) * 8]);
            #pragma unroll
            for (int j = 0; j < 4; ++j) {
                bf16x8 b = *reinterpret_cast<const bf16x8*>(&Bs[wc * 64 + j * 16 + (lane & 15)][ks + (lane >> 4) * 8]);
                acc[mr][j] = __builtin_amdgcn_mfma_f32_16x16x32_bf16(a, b, acc[mr][j], 0, 0, 0);
            }
        }
    }

    const float om = 1.f - theta;
    const int cb = wc * 64 + (lane & 15);
    #pragma unroll
    for (int mr = 0; mr < 2; ++mr) {
        const int rloc = wr * 32 + mr * 16 + ((lane >> 4) << 2);
        #pragma unroll
        for (int j = 0; j < 4; ++j) {
            int col = cb + j * 16;
            #pragma unroll
            for (int i = 0; i < 4; ++i) {
                int gr = r0 + rloc + i;
                if (gr < N_NODES) {
                    float s = bf16tof(As[rloc + i][col]);
                    float v = fmaxf(fmaf(theta, acc[mr][j][i], om * s), 0.f);
                    if (fout) fout[(size_t)gr * NHID + col] = v;
                    else      hb[(size_t)gr * NHID + col] = bf16s(v);
                }
            }
        }
    }
}

// ---------------------------------------------------------------------------
// SpMM + residual: sb[n,:] = bf16(0.9 * sum_e vals[e]*hb[cols[e],:] + 0.1*h0b[n,:])
// One wave per node, FOUR 16-lane quarters process edges 4t+q; each quarter
// reads a full 256B row as uint4/lane -> 4 edges in flight per issue slot.
// ---------------------------------------------------------------------------
__global__ void spmm_kernel(const uint4* __restrict__ hb4, const uint4* __restrict__ h0b4,
                            const int* __restrict__ rowptr, const int* __restrict__ cols,
                            const float* __restrict__ vals, uint4* __restrict__ sb4) {
    const int node = blockIdx.x * 4 + (threadIdx.x >> 6);
    const int lane = threadIdx.x & 63;
    const int q = lane >> 4;          // edge parity quarter
    const int l = lane & 15;          // feature octet: features 8l..8l+7

    const int e0 = rowptr[node], e1 = rowptr[node + 1];

    float a0 = 0.f, a1 = 0.f, a2 = 0.f, a3 = 0.f;
    float a4 = 0.f, a5 = 0.f, a6 = 0.f, a7 = 0.f;
    for (int base = e0; base < e1; base += 64) {
        int m = e1 - base; if (m > 64) m = 64;
        int c = 0; float v = 0.f;
        if (lane < m) { c = cols[base + lane]; v = vals[base + lane]; }
        const int nt = (m + 3) >> 2;
        #pragma unroll 8
        for (int t = 0; t < nt; ++t) {
            int j = 4 * t + q;
            int jc = (j < m) ? j : 0;
            int   cj = __shfl(c, jc);
            float vj = __shfl(v, jc);
            if (j >= m) vj = 0.f;
            uint4 hv = hb4[(size_t)cj * 16 + l];
            a0 = fmaf(vj, bflo(hv.x), a0);
            a1 = fmaf(vj, bfhi(hv.x), a1);
            a2 = fmaf(vj, bflo(hv.y), a2);
            a3 = fmaf(vj, bfhi(hv.y), a3);
            a4 = fmaf(vj, bflo(hv.z), a4);
            a5 = fmaf(vj, bfhi(hv.z), a5);
            a6 = fmaf(vj, bflo(hv.w), a6);
            a7 = fmaf(vj, bfhi(hv.w), a7);
        }
    }
    // combine the four quarters
    a0 += __shfl_xor(a0, 16); a1 += __shfl_xor(a1, 16);
    a2 += __shfl_xor(a2, 16); a3 += __shfl_xor(a3, 16);
    a4 += __shfl_xor(a4, 16); a5 += __shfl_xor(a5, 16);
    a6 += __shfl_xor(a6, 16); a7 += __shfl_xor(a7, 16);
    a0 += __shfl_xor(a0, 32); a1 += __shfl_xor(a1, 32);
    a2 += __shfl_xor(a2, 32); a3 += __shfl_xor(a3, 32);
    a4 += __shfl_xor(a4, 32); a5 += __shfl_xor(a5, 32);
    a6 += __shfl_xor(a6, 32); a7 += __shfl_xor(a7, 32);

    if (q == 0) {
        uint4 h0v = h0b4[(size_t)node * 16 + l];
        uint4 o;
        o.x = bf16pack(0.9f * a0 + 0.1f * bflo(h0v.x), 0.9f * a1 + 0.1f * bfhi(h0v.x));
        o.y = bf16pack(0.9f * a2 + 0.1f * bflo(h0v.y), 0.9f * a3 + 0.1f * bfhi(h0v.y));
        o.z = bf16pack(0.9f * a4 + 0.1f * bflo(h0v.z), 0.9f * a5 + 0.1f * bfhi(h0v.z));
        o.w = bf16pack(0.9f * a6 + 0.1f * bflo(h0v.w), 0.9f * a7 + 0.1f * bfhi(h0v.w));
        sb4[(size_t)node * 16 + l] = o;
    }
}

// ---------------------------------------------------------------------------
// final: logits = h @ fc2_w + b; out0 = log_softmax; out2 = [h, logits]
// ---------------------------------------------------------------------------
__global__ void final_kernel(const float* __restrict__ h, const float* __restrict__ w,
                             const float* __restrict__ b, float* __restrict__ out0,
                             float* __restrict__ out2) {
    __shared__ float hs[4][128];
    const int s = threadIdx.x >> 6;
    const int lane = threadIdx.x & 63;
    const int node = blockIdx.x * 4 + s;

    float h_lo = h[node * NHID + lane];
    float h_hi = h[node * NHID + 64 + lane];
    hs[s][lane] = h_lo;
    hs[s][64 + lane] = h_hi;
    __syncthreads();

    float logit = 0.f;
    if (lane < NCLASS) {
        logit = b[lane];
        #pragma unroll 8
        for (int k = 0; k < NHID; ++k)
            logit = fmaf(hs[s][k], w[k * NCLASS + lane], logit);
    }

    float mv = (lane < NCLASS) ? logit : -1e30f;
    #pragma unroll
    for (int m = 32; m; m >>= 1) mv = fmaxf(mv, __shfl_xor(mv, m));
    float ev = (lane < NCLASS) ? __expf(logit - mv) : 0.f;
    float sum = ev;
    #pragma unroll
    for (int m = 32; m; m >>= 1) sum += __shfl_xor(sum, m);
    float lse = mv + __logf(sum);

    if (lane < NCLASS) {
        out0[node * NCLASS + lane] = logit - lse;
        out2[node * 168 + 128 + lane] = logit;
    }
    out2[node * 168 + lane] = h_lo;
    out2[node * 168 + 64 + lane] = h_hi;
}

// ---------------------------------------------------------------------------
extern "C" void kernel_launch(void* const* d_in, const int* in_sizes, int n_in,
                              void* d_out, int out_size, void* d_ws, size_t ws_size,
                              hipStream_t stream) {
    const float* x      = (const float*)d_in[0];
    const int*   rows   = (const int*)  d_in[1];
    const int*   cols   = (const int*)  d_in[2];
    const float* vals   = (const float*)d_in[3];
    const float* fc1_w  = (const float*)d_in[4];
    const float* fc1_b  = (const float*)d_in[5];
    const float* conv_w = (const float*)d_in[6];
    const float* fc2_w  = (const float*)d_in[7];
    const float* fc2_b  = (const float*)d_in[8];
    float* out = (float*)d_out;

    const int nE = in_sizes[1];
    const size_t NH = (size_t)N_NODES * NHID;   // 12.8M elements
    const size_t PAD = 64 * NHID;               // tail padding for BM=64 A-staging

    // workspace layout
    char* p = (char*)d_ws;
    int*    rowptr = (int*)p;          p += 400128;            // 100001 ints, padded
    ushort* h0b    = (ushort*)p;       p += NH * 2;            // 25.6 MB
    ushort* hb     = (ushort*)p;       p += (NH + PAD) * 2;    // 25.6 MB + 16KB
    ushort* sb     = (ushort*)p;       p += (NH + PAD) * 2;    // 25.6 MB + 16KB
    ushort* wT1    = (ushort*)p;       p += 65536 * 2;         // 128 KB
    ushort* wTc    = (ushort*)p;       p += 65536 * 2;         // 128 KB

    // out regions
    float* out0 = out;                                  // [N,40]
    float* out1 = out + (size_t)N_NODES * NCLASS;       // [N,128] final h (f32)
    float* out2 = out1 + NH;                            // [N,168]

    prep_weights<<<256, 256, 0, stream>>>(fc1_w, conv_w, wT1, wTc);
    rowptr_kernel<<<(N_NODES + 1 + 255) / 256, 256, 0, stream>>>(rows, rowptr, nE);
    fc1_mfma<<<N_NODES / 32, 256, 0, stream>>>(x, (const uint*)wT1, fc1_b, h0b);

    for (int i = 0; i < 4; ++i) {
        float theta = logf(0.5f / (float)(i + 1) + 1.0f);
        spmm_kernel<<<N_NODES / 4, 256, 0, stream>>>(
            (const uint4*)(i == 0 ? h0b : hb), (const uint4*)h0b, rowptr, cols, vals, (uint4*)sb);
        layer_mfma<<<(N_NODES + 63) / 64, 256, 0, stream>>>(
            (const uint*)sb, (const uint*)(wTc + (size_t)i * 16384), theta,
            (i < 3) ? hb : nullptr, (i == 3) ? out1 : nullptr);
    }

    final_kernel<<<N_NODES / 4, 256, 0, stream>>>(out1, fc2_w, fc2_b, out0, out2);
}